// Round 1
// baseline (84.112 us; speedup 1.0000x reference)
//
#include <hip/hip_runtime.h>

// Problem constants (fixed shapes from reference)
#define NB 64       // batches
#define NN 2048     // users per batch
#define ED 128      // embedding dim
#define NT 63       // c3 length (K2-1)
#define WAVES 4
#define NBLOCKS_C 2048
#define TOTWAVES (NBLOCKS_C * WAVES)          // 8192
#define ITERS ((NB * NN) / TOTWAVES)          // 16

// workspace layout (float offsets)
#define WS_WEFF  0                 // 64 (weff[63], [63]=0)
#define WS_BEFF  64                // 1
#define WS_W3RC  128               // 128: interleaved {W3row0[j], W3row2[j]}
#define WS_SHIGH 256               // 64
#define WS_QTERM 320               // 64*64
#define WS_QPRE  (320 + 64*64)     // 64*128
#define WS_PART  (WS_QPRE + 64*128) // NBLOCKS_C

// ---------------- Kernel A: collapse MLP + repack W3 ----------------
__global__ __launch_bounds__(64) void k_combine(
    const float* __restrict__ fw1, const float* __restrict__ fb1,
    const float* __restrict__ fw2, const float* __restrict__ fb2,
    const float* __restrict__ fw3, const float* __restrict__ fb3,
    const float* __restrict__ W3,
    float* __restrict__ ws)
{
    __shared__ float g[16];
    const int t = threadIdx.x;
    if (t < 16) {
        float s = 0.f;
        for (int i = 0; i < 16; ++i) s += fw3[i] * fw2[i*16 + t];
        g[t] = s;
    }
    __syncthreads();
    float wv = 0.f;
    if (t < 63) {
        for (int k = 0; k < 16; ++k) wv += g[k] * fw1[k*63 + t];
    }
    ws[WS_WEFF + t] = wv;             // weff[63] = 0 masks the pad lane
    ws[WS_W3RC + 2*t]     = W3[t];        // row 0
    ws[WS_W3RC + 2*t + 1] = W3[128 + t];  // row 2
    if (t == 0) {
        float be = fb3[0];
        for (int i = 0; i < 16; ++i) be += fw3[i] * fb2[i];
        for (int k = 0; k < 16; ++k) be += g[k] * fb1[k];
        ws[WS_BEFF] = be;
    }
}

// ---------------- Kernel B: per-batch precompute + high score ----------------
__global__ __launch_bounds__(64) void k_batch(
    const float* __restrict__ top_user, const float* __restrict__ question,
    const float* __restrict__ W1, const float* __restrict__ b1,
    const float* __restrict__ W2, const float* __restrict__ b2,
    const float* __restrict__ W3, const float* __restrict__ b3,
    float* __restrict__ ws)
{
    __shared__ float q[132], tu[132], c1q[128], qt[64];
    __shared__ float4 D4[64];
    const int b = blockIdx.x, lane = threadIdx.x;
    ((float2*)q)[lane]  = ((const float2*)(question + b*ED))[lane];
    ((float2*)tu)[lane] = ((const float2*)(top_user + b*ED))[lane];
    if (lane == 63) {
        q[128]=0.f; q[129]=0.f; q[130]=0.f; q[131]=0.f;
        tu[128]=0.f; tu[129]=0.f; tu[130]=0.f; tu[131]=0.f;
    }
    __syncthreads();
    const float w10=W1[0], w11=W1[1], w12=W1[2];
    const float w20=W2[0], w21=W2[1], w22=W2[2];
    const float w23=W2[3], w24=W2[4], w25=W2[5];
    const float b1v=b1[0], b2v=b2[0], b3v=b3[0];
    const int i = 2*lane;
    float c1qa = fmaxf(b1v + w10*q[i]   + w11*q[i+1] + w12*q[i+2], 0.f);
    float c1qb = fmaxf(b1v + w10*q[i+1] + w11*q[i+2] + w12*q[i+3], 0.f);
    float qpa  = w23*q[i]   + w24*q[i+1] + w25*q[i+2];
    float qpb  = w23*q[i+1] + w24*q[i+2] + w25*q[i+3];
    float c1ta = fmaxf(b1v + w10*tu[i]   + w11*tu[i+1] + w12*tu[i+2], 0.f);
    float c1tb = fmaxf(b1v + w10*tu[i+1] + w11*tu[i+2] + w12*tu[i+3], 0.f);
    float c2a  = fmaxf(b2v + w20*tu[i]   + w21*tu[i+1] + w22*tu[i+2] + qpa, 0.f);
    float c2b  = fmaxf(b2v + w20*tu[i+1] + w21*tu[i+2] + w22*tu[i+3] + qpb, 0.f);
    if (lane == 63) { c1qa=0.f; c1qb=0.f; qpa=0.f; qpb=0.f; c1ta=0.f; c1tb=0.f; c2a=0.f; c2b=0.f; }
    c1q[i] = c1qa; c1q[i+1] = c1qb;
    ws[WS_QPRE + b*128 + i]     = qpa;
    ws[WS_QPRE + b*128 + i + 1] = qpb;
    D4[lane] = make_float4(c1ta, c2a, c1tb, c2b);
    __syncthreads();
    float qtv = 0.f;
    if (lane < 63) {
        for (int j = 0; j < 64; ++j) qtv += W3[64 + j] * c1q[lane + j];
    }
    qt[lane] = qtv;
    ws[WS_QTERM + b*64 + lane] = qtv;
    __syncthreads();
    // high score for this batch
    float acc0 = b3v + qt[lane];
    float acc1 = 0.f;
    const float2* D2 = (const float2*)D4;
    #pragma unroll
    for (int j = 0; j < 64; ++j) {
        const float2 d = D2[lane + j];
        acc0 = fmaf(W3[j],       d.x, acc0);
        acc1 = fmaf(W3[128 + j], d.y, acc1);
    }
    float v = ws[WS_WEFF + lane] * fmaxf(acc0 + acc1, 0.f);
    #pragma unroll
    for (int off = 32; off > 0; off >>= 1) v += __shfl_xor(v, off, 64);
    if (lane == 0) ws[WS_SHIGH + b] = v + ws[WS_BEFF];
}

// ---------------- Kernel C: all pairs ----------------
struct Slice {
    float4 D4[64];   // interleaved {c1u[2i], c2[2i], c1u[2i+1], c2[2i+1]}
    float  u[132];
};

__global__ __launch_bounds__(256) void k_pairs(
    const float* __restrict__ users, const int* __restrict__ uids,
    float* __restrict__ ws,
    const float* __restrict__ W1, const float* __restrict__ b1,
    const float* __restrict__ W2, const float* __restrict__ b2,
    const float* __restrict__ b3)
{
    __shared__ Slice sl[WAVES];
    __shared__ float wsum[WAVES];
    const int tid = threadIdx.x;
    const int w = tid >> 6, lane = tid & 63;
    const int gw = blockIdx.x * WAVES + w;
    const float w10=W1[0], w11=W1[1], w12=W1[2];
    const float w20=W2[0], w21=W2[1], w22=W2[2];
    const float b1v=b1[0], b2v=b2[0], b3v=b3[0];
    const float weffl = ws[WS_WEFF + lane];
    const float beff  = ws[WS_BEFF];
    float wacc = 0.f;

    for (int it = 0; it < ITERS; ++it) {
        const int p = gw + it * TOTWAVES;
        const int b = p >> 11;                  // NN = 2048
        const bool act = (uids[p] != 0);        // wave-uniform
        if (act) {
            float2* u2 = (float2*)sl[w].u;
            u2[lane] = ((const float2*)(users + (size_t)p * ED))[lane];
            if (lane == 63) {
                sl[w].u[128]=0.f; sl[w].u[129]=0.f; sl[w].u[130]=0.f; sl[w].u[131]=0.f;
            }
        }
        __syncthreads();
        if (act) {
            const float* u = sl[w].u;
            const int i = 2*lane;
            const float u0=u[i], u1=u[i+1], u2v=u[i+2], u3v=u[i+3];
            const float2 qp = *(const float2*)&ws[WS_QPRE + b*128 + i];
            float c1a = fmaxf(b1v + w10*u0 + w11*u1  + w12*u2v, 0.f);
            float c1b = fmaxf(b1v + w10*u1 + w11*u2v + w12*u3v, 0.f);
            float c2a = fmaxf(b2v + w20*u0 + w21*u1  + w22*u2v + qp.x, 0.f);
            float c2b = fmaxf(b2v + w20*u1 + w21*u2v + w22*u3v + qp.y, 0.f);
            if (lane == 63) { c1a=0.f; c1b=0.f; c2a=0.f; c2b=0.f; }
            sl[w].D4[lane] = make_float4(c1a, c2a, c1b, c2b);
        }
        __syncthreads();
        if (act) {
            const float2* D2 = (const float2*)sl[w].D4;
            float acc0 = b3v + ws[WS_QTERM + b*64 + lane];
            float acc1 = 0.f;
            #pragma unroll
            for (int j = 0; j < 64; ++j) {
                const float2 d  = D2[lane + j];
                const float2 wj = *(const float2*)&ws[WS_W3RC + 2*j];
                acc0 = fmaf(wj.x, d.x, acc0);
                acc1 = fmaf(wj.y, d.y, acc1);
            }
            float v = weffl * fmaxf(acc0 + acc1, 0.f);   // weff[63]=0 masks lane 63
            #pragma unroll
            for (int off = 32; off > 0; off >>= 1) v += __shfl_xor(v, off, 64);
            const float dlt = (v + beff) - ws[WS_SHIGH + b];
            wacc += 1.f / (1.f + __expf(-dlt));
        }
        __syncthreads();
    }
    if (lane == 0) wsum[w] = wacc;
    __syncthreads();
    if (tid == 0) ws[WS_PART + blockIdx.x] = wsum[0] + wsum[1] + wsum[2] + wsum[3];
}

// ---------------- Kernel D: final reduce ----------------
__global__ __launch_bounds__(256) void k_reduce(const float* __restrict__ ws, float* __restrict__ out)
{
    __shared__ float sh[4];
    float s = 0.f;
    for (int i = threadIdx.x; i < NBLOCKS_C; i += 256) s += ws[WS_PART + i];
    #pragma unroll
    for (int off = 32; off > 0; off >>= 1) s += __shfl_xor(s, off, 64);
    if ((threadIdx.x & 63) == 0) sh[threadIdx.x >> 6] = s;
    __syncthreads();
    if (threadIdx.x == 0) out[0] = sh[0] + sh[1] + sh[2] + sh[3];
}

extern "C" void kernel_launch(void* const* d_in, const int* in_sizes, int n_in,
                              void* d_out, int out_size, void* d_ws, size_t ws_size,
                              hipStream_t stream)
{
    const float* users    = (const float*)d_in[0];
    const float* top_user = (const float*)d_in[1];
    const float* question = (const float*)d_in[2];
    const int*   uids     = (const int*)d_in[3];
    const float* W1  = (const float*)d_in[4];
    const float* b1  = (const float*)d_in[5];
    const float* W2  = (const float*)d_in[6];
    const float* b2  = (const float*)d_in[7];
    const float* W3  = (const float*)d_in[8];
    const float* b3  = (const float*)d_in[9];
    const float* fw1 = (const float*)d_in[10];
    const float* fb1 = (const float*)d_in[11];
    const float* fw2 = (const float*)d_in[12];
    const float* fb2 = (const float*)d_in[13];
    const float* fw3 = (const float*)d_in[14];
    const float* fb3 = (const float*)d_in[15];
    float* ws  = (float*)d_ws;
    float* out = (float*)d_out;

    hipLaunchKernelGGL(k_combine, dim3(1), dim3(64), 0, stream,
                       fw1, fb1, fw2, fb2, fw3, fb3, W3, ws);
    hipLaunchKernelGGL(k_batch, dim3(NB), dim3(64), 0, stream,
                       top_user, question, W1, b1, W2, b2, W3, b3, ws);
    hipLaunchKernelGGL(k_pairs, dim3(NBLOCKS_C), dim3(256), 0, stream,
                       users, uids, ws, W1, b1, W2, b2, b3);
    hipLaunchKernelGGL(k_reduce, dim3(1), dim3(256), 0, stream, ws, out);
}

// Round 2
// 56.016 us; speedup vs baseline: 1.5016x; 1.5016x over previous
//
#include <hip/hip_runtime.h>
#include <hip/hip_bf16.h>

typedef __attribute__((ext_vector_type(8))) short short8v;
typedef __attribute__((ext_vector_type(4))) float float4v;
typedef __attribute__((ext_vector_type(4))) unsigned int uint4v;

// Problem constants
#define NB 64
#define NN 2048
#define ED 128
#define CHUNK 64
#define NCHUNK (NN/CHUNK)     // 32
#define GRID_C (NB*NCHUNK)    // 2048

// workspace layout (float offsets)
#define WS_WEFF  0                  // 64 (weff[63], [63]=0)
#define WS_BEFF  64                 // 1
#define WS_SHIGH 128                // 64
#define WS_QTERM 192                // 64*64  (qterm + b3 folded)
#define WS_QPRE  (192+4096)         // 64*128
#define WS_PART  (WS_QPRE+8192)     // 2048
#define WS_BPACK (WS_PART+2048)     // bf16[16384] = 4096 floats, 16B aligned

// ---------------- Kernel A: collapse MLP + build Toeplitz B-pack ----------------
__global__ __launch_bounds__(256) void k_combine(
    const float* __restrict__ fw1, const float* __restrict__ fb1,
    const float* __restrict__ fw2, const float* __restrict__ fb2,
    const float* __restrict__ fw3, const float* __restrict__ fb3,
    const float* __restrict__ W3,
    float* __restrict__ ws)
{
    __shared__ float g[16];
    const int t = threadIdx.x;
    if (t < 16) {
        float s = 0.f;
        for (int i = 0; i < 16; ++i) s += fw3[i] * fw2[i*16 + t];
        g[t] = s;
    }
    __syncthreads();
    if (t < 64) {
        float wv = 0.f;
        if (t < 63) {
            for (int k = 0; k < 16; ++k) wv += g[k] * fw1[k*63 + t];
        }
        ws[WS_WEFF + t] = wv;          // weff[63] = 0 masks pad tap
        if (t == 0) {
            float be = fb3[0];
            for (int i = 0; i < 16; ++i) be += fw3[i] * fb2[i];
            for (int k = 0; k < 16; ++k) be += g[k] * fb1[k];
            ws[WS_BEFF] = be;
        }
    }
    // B-pack: B[k][t], k=0..255 (k=2d..2d+1 of X rows), t=0..63 (tap; 63=pad)
    // fragment order: bp[((kt*4+nt)*64+lane)*8+idx] = B[kt*32+8*(lane>>4)+idx][nt*16+(lane&15)]
    __hip_bfloat16* bp = (__hip_bfloat16*)(ws + WS_BPACK);
    const int lane = t & 63, grp = t >> 6;
    for (int q = 0; q < 2; ++q) {
        const int kt = grp*2 + q;
        for (int nt = 0; nt < 4; ++nt) {
            for (int idx = 0; idx < 8; ++idx) {
                const int k  = kt*32 + (lane >> 4)*8 + idx;
                const int tt = nt*16 + (lane & 15);
                float v = 0.f;
                if (tt < 63) {
                    const int j = k - tt;
                    if (k < 126 && j >= 0 && j < 64) v = W3[j];           // c1u row
                    else {
                        const int k2 = k - 128, j2 = k2 - tt;
                        if (k2 >= 0 && k2 < 126 && j2 >= 0 && j2 < 64) v = W3[128 + j2]; // c2 row
                    }
                }
                bp[((kt*4 + nt)*64 + lane)*8 + idx] = __float2bfloat16(v);
            }
        }
    }
}

// ---------------- Kernel B: per-batch precompute + high score ----------------
__global__ __launch_bounds__(64) void k_batch(
    const float* __restrict__ top_user, const float* __restrict__ question,
    const float* __restrict__ W1, const float* __restrict__ b1,
    const float* __restrict__ W2, const float* __restrict__ b2,
    const float* __restrict__ W3, const float* __restrict__ b3,
    float* __restrict__ ws)
{
    __shared__ float q[132], tu[132], c1q[128], qt[64];
    __shared__ float4 D4[64];
    const int b = blockIdx.x, lane = threadIdx.x;
    ((float2*)q)[lane]  = ((const float2*)(question + b*ED))[lane];
    ((float2*)tu)[lane] = ((const float2*)(top_user + b*ED))[lane];
    if (lane == 63) {
        q[128]=0.f; q[129]=0.f; q[130]=0.f; q[131]=0.f;
        tu[128]=0.f; tu[129]=0.f; tu[130]=0.f; tu[131]=0.f;
    }
    __syncthreads();
    const float w10=W1[0], w11=W1[1], w12=W1[2];
    const float w20=W2[0], w21=W2[1], w22=W2[2];
    const float w23=W2[3], w24=W2[4], w25=W2[5];
    const float b1v=b1[0], b2v=b2[0], b3v=b3[0];
    const int i = 2*lane;
    float c1qa = fmaxf(b1v + w10*q[i]   + w11*q[i+1] + w12*q[i+2], 0.f);
    float c1qb = fmaxf(b1v + w10*q[i+1] + w11*q[i+2] + w12*q[i+3], 0.f);
    float qpa  = w23*q[i]   + w24*q[i+1] + w25*q[i+2];
    float qpb  = w23*q[i+1] + w24*q[i+2] + w25*q[i+3];
    float c1ta = fmaxf(b1v + w10*tu[i]   + w11*tu[i+1] + w12*tu[i+2], 0.f);
    float c1tb = fmaxf(b1v + w10*tu[i+1] + w11*tu[i+2] + w12*tu[i+3], 0.f);
    float c2a  = fmaxf(b2v + w20*tu[i]   + w21*tu[i+1] + w22*tu[i+2] + qpa, 0.f);
    float c2b  = fmaxf(b2v + w20*tu[i+1] + w21*tu[i+2] + w22*tu[i+3] + qpb, 0.f);
    if (lane == 63) { c1qa=0.f; c1qb=0.f; qpa=0.f; qpb=0.f; c1ta=0.f; c1tb=0.f; c2a=0.f; c2b=0.f; }
    c1q[i] = c1qa; c1q[i+1] = c1qb;
    ws[WS_QPRE + b*128 + i]     = qpa;
    ws[WS_QPRE + b*128 + i + 1] = qpb;
    D4[lane] = make_float4(c1ta, c2a, c1tb, c2b);
    __syncthreads();
    float qtv = 0.f;
    if (lane < 63) {
        for (int j = 0; j < 64; ++j) qtv += W3[64 + j] * c1q[lane + j];
    }
    qt[lane] = qtv;
    ws[WS_QTERM + b*64 + lane] = qtv + b3v;   // fold b3 for GEMM epilogue
    __syncthreads();
    float acc0 = b3v + qt[lane];
    float acc1 = 0.f;
    const float2* D2 = (const float2*)D4;
    #pragma unroll
    for (int j = 0; j < 64; ++j) {
        const float2 d = D2[lane + j];
        acc0 = fmaf(W3[j],       d.x, acc0);
        acc1 = fmaf(W3[128 + j], d.y, acc1);
    }
    float v = ws[WS_WEFF + lane] * fmaxf(acc0 + acc1, 0.f);
    #pragma unroll
    for (int off = 32; off > 0; off >>= 1) v += __shfl_xor(v, off, 64);
    if (lane == 0) ws[WS_SHIGH + b] = v + ws[WS_BEFF];
}

// ---------------- Kernel C: pairs via MFMA GEMM ----------------
__global__ __launch_bounds__(256) void k_pairs(
    const float* __restrict__ users, const int* __restrict__ uids,
    float* __restrict__ ws,
    const float* __restrict__ W1, const float* __restrict__ b1,
    const float* __restrict__ W2, const float* __restrict__ b2)
{
    // X: 64 pairs x 264 bf16 (k=0..255 valid, stride 132 dwords == 4 mod 32 -> 2-way free)
    __shared__ __align__(16) unsigned int X[64][132];   // 33792 B
    __shared__ uint4v Bp[2048];                         // 32768 B
    __shared__ float pscore[2][64];
    const int tid = threadIdx.x;
    const int w = tid >> 6, lane = tid & 63;
    const int bid = blockIdx.x;
    const int b = bid >> 5;            // / NCHUNK
    const int chunk = bid & 31;
    const int base = b*NN + chunk*CHUNK;

    // prefix property: uids nonzero exactly for n < length
    if (uids[base] == 0) {
        if (tid == 0) ws[WS_PART + bid] = 0.f;
        return;
    }

    // stage B-pack into LDS (coalesced, one-time 32 KB)
    const uint4v* bsrc = (const uint4v*)(ws + WS_BPACK);
    #pragma unroll
    for (int it = 0; it < 8; ++it) Bp[it*256 + tid] = bsrc[it*256 + tid];

    // early loads (hide latency under prep)
    const int g = lane >> 4, li = lane & 15;
    const int nhalf = w >> 1;            // tap half
    const int mbase = (w & 1) * 32;      // pair half
    const int t0 = nhalf*32 + li, t1 = t0 + 16;
    const float wf0 = ws[WS_WEFF + t0], wf1 = ws[WS_WEFF + t1];
    const float qt0 = ws[WS_QTERM + b*64 + t0], qt1 = ws[WS_QTERM + b*64 + t1];
    const float shigh = ws[WS_SHIGH + b], beff = ws[WS_BEFF];
    const float2 qp = *(const float2*)&ws[WS_QPRE + b*128 + 2*lane];
    const float w10=W1[0], w11=W1[1], w12=W1[2];
    const float w20=W2[0], w21=W2[1], w22=W2[2];
    const float b1v=b1[0], b2v=b2[0];

    // X-prep: wave w computes rows w*16 .. w*16+15
    const int rbase = w * 16;
    if (lane < 63) {
        #pragma unroll 4
        for (int r = 0; r < 16; ++r) {
            const float* up = users + (size_t)(base + rbase + r)*ED + 2*lane;
            const float2 ua = *(const float2*)up;
            const float2 ub = *(const float2*)(up + 2);
            float c1a = fmaxf(b1v + w10*ua.x + w11*ua.y + w12*ub.x, 0.f);
            float c1b = fmaxf(b1v + w10*ua.y + w11*ub.x + w12*ub.y, 0.f);
            float c2a = fmaxf(b2v + w20*ua.x + w21*ua.y + w22*ub.x + qp.x, 0.f);
            float c2b = fmaxf(b2v + w20*ua.y + w21*ub.x + w22*ub.y + qp.y, 0.f);
            __hip_bfloat162 h1 = __float22bfloat162_rn(make_float2(c1a, c1b));
            __hip_bfloat162 h2 = __float22bfloat162_rn(make_float2(c2a, c2b));
            X[rbase + r][lane]      = *(unsigned int*)&h1;
            X[rbase + r][64 + lane] = *(unsigned int*)&h2;
        }
    } else {
        #pragma unroll
        for (int r = 0; r < 16; ++r) { X[rbase + r][63] = 0u; X[rbase + r][127] = 0u; }
    }
    __syncthreads();

    // GEMM: wave quadrant = 32 pairs x 32 taps, K=256
    float4v acc00 = {0.f,0.f,0.f,0.f}, acc01 = {0.f,0.f,0.f,0.f};
    float4v acc10 = {0.f,0.f,0.f,0.f}, acc11 = {0.f,0.f,0.f,0.f};
    const char* Xb = (const char*)&X[0][0];
    #pragma unroll
    for (int kt = 0; kt < 8; ++kt) {
        const short8v a0 = *(const short8v*)(Xb + (mbase + li)*528      + kt*64 + g*16);
        const short8v a1 = *(const short8v*)(Xb + (mbase + 16 + li)*528 + kt*64 + g*16);
        const short8v bb0 = *(const short8v*)&Bp[(kt*4 + nhalf*2 + 0)*64 + lane];
        const short8v bb1 = *(const short8v*)&Bp[(kt*4 + nhalf*2 + 1)*64 + lane];
        acc00 = __builtin_amdgcn_mfma_f32_16x16x32_bf16(a0, bb0, acc00, 0, 0, 0);
        acc01 = __builtin_amdgcn_mfma_f32_16x16x32_bf16(a0, bb1, acc01, 0, 0, 0);
        acc10 = __builtin_amdgcn_mfma_f32_16x16x32_bf16(a1, bb0, acc10, 0, 0, 0);
        acc11 = __builtin_amdgcn_mfma_f32_16x16x32_bf16(a1, bb1, acc11, 0, 0, 0);
    }

    // epilogue: score partial over this wave's 32 taps for its 32 pairs
    #pragma unroll
    for (int mi = 0; mi < 2; ++mi) {
        #pragma unroll
        for (int reg = 0; reg < 4; ++reg) {
            const float a0v = mi ? acc10[reg] : acc00[reg];
            const float a1v = mi ? acc11[reg] : acc01[reg];
            float v = wf0 * fmaxf(a0v + qt0, 0.f) + wf1 * fmaxf(a1v + qt1, 0.f);
            v += __shfl_xor(v, 1, 64);
            v += __shfl_xor(v, 2, 64);
            v += __shfl_xor(v, 4, 64);
            v += __shfl_xor(v, 8, 64);
            if (li == 0) pscore[nhalf][mbase + mi*16 + g*4 + reg] = v;
        }
    }
    __syncthreads();

    if (w == 0) {
        const float d = pscore[0][lane] + pscore[1][lane] + beff - shigh;
        float val = (uids[base + lane] != 0) ? 1.f / (1.f + __expf(-d)) : 0.f;
        #pragma unroll
        for (int off = 32; off > 0; off >>= 1) val += __shfl_xor(val, off, 64);
        if (lane == 0) ws[WS_PART + bid] = val;
    }
}

// ---------------- Kernel D: final reduce ----------------
__global__ __launch_bounds__(256) void k_reduce(const float* __restrict__ ws, float* __restrict__ out)
{
    __shared__ float sh[4];
    float s = 0.f;
    for (int i = threadIdx.x; i < GRID_C; i += 256) s += ws[WS_PART + i];
    #pragma unroll
    for (int off = 32; off > 0; off >>= 1) s += __shfl_xor(s, off, 64);
    if ((threadIdx.x & 63) == 0) sh[threadIdx.x >> 6] = s;
    __syncthreads();
    if (threadIdx.x == 0) out[0] = sh[0] + sh[1] + sh[2] + sh[3];
}

extern "C" void kernel_launch(void* const* d_in, const int* in_sizes, int n_in,
                              void* d_out, int out_size, void* d_ws, size_t ws_size,
                              hipStream_t stream)
{
    const float* users    = (const float*)d_in[0];
    const float* top_user = (const float*)d_in[1];
    const float* question = (const float*)d_in[2];
    const int*   uids     = (const int*)d_in[3];
    const float* W1  = (const float*)d_in[4];
    const float* b1  = (const float*)d_in[5];
    const float* W2  = (const float*)d_in[6];
    const float* b2  = (const float*)d_in[7];
    const float* W3  = (const float*)d_in[8];
    const float* b3  = (const float*)d_in[9];
    const float* fw1 = (const float*)d_in[10];
    const float* fb1 = (const float*)d_in[11];
    const float* fw2 = (const float*)d_in[12];
    const float* fb2 = (const float*)d_in[13];
    const float* fw3 = (const float*)d_in[14];
    const float* fb3 = (const float*)d_in[15];
    float* ws  = (float*)d_ws;
    float* out = (float*)d_out;

    hipLaunchKernelGGL(k_combine, dim3(1), dim3(256), 0, stream,
                       fw1, fb1, fw2, fb2, fw3, fb3, W3, ws);
    hipLaunchKernelGGL(k_batch, dim3(NB), dim3(64), 0, stream,
                       top_user, question, W1, b1, W2, b2, W3, b3, ws);
    hipLaunchKernelGGL(k_pairs, dim3(GRID_C), dim3(256), 0, stream,
                       users, uids, ws, W1, b1, W2, b2);
    hipLaunchKernelGGL(k_reduce, dim3(1), dim3(256), 0, stream, ws, out);
}